// Round 5
// baseline (24699.081 us; speedup 1.0000x reference)
//
#include <hip/hip_runtime.h>
#include <cstdint>
#include <cstddef>

// ---------------- problem constants ----------------
#define B_   32
#define S_   1024
#define IN_  128
#define H_   512
#define OUT_ 128
#define NL_  3
#define NWG_LAYER 96            // 3 layers x 32 n-tiles
#define NWG_TOT   104           // + 8 output-projection WGs
#define NSTEP (S_ + NL_)        // 1027 pipeline steps

typedef __attribute__((ext_vector_type(8))) short short8;   // 8 bf16 (4 VGPRs)
typedef __attribute__((ext_vector_type(4))) float floatx4;  // MFMA C/D

// ---------------- workspace layout (bytes); total ~12.6 MB ----------------
constexpr size_t OFF_BAR  = 0;                        // arrive[104] packed 4B (7 lines)
constexpr size_t OFF_W0Z  = 8192;                     // 512x128 bf16
constexpr size_t OFF_W0R  = OFF_W0Z + 131072;
constexpr size_t OFF_W0G  = OFF_W0R + 131072;
constexpr size_t OFF_WXZ  = OFF_W0G + 131072;         // 512x512 bf16 each
constexpr size_t OFF_WXR  = OFF_WXZ + 524288;
constexpr size_t OFF_WXG  = OFF_WXR + 524288;
constexpr size_t OFF_WHZ  = OFF_WXG + 524288;
constexpr size_t OFF_WHR  = OFF_WHZ + 524288;
constexpr size_t OFF_WHG  = OFF_WHR + 524288;
constexpr size_t OFF_WOUT = OFF_WHG + 524288;         // 128x512 bf16
constexpr size_t OFF_XBF  = OFF_WOUT + 131072;        // x bf16 [32][1024][128]
constexpr size_t OFF_HST  = OFF_XBF + 8388608;        // f32 h state [3][32][512] (WG-private strips)
constexpr size_t OFF_HBF  = OFF_HST + 196608;         // bf16 h double-buf [3][2][32][512] (cross-WG, sc1)
constexpr size_t OFF_RH   = OFF_HBF + 196608;         // bf16 r*h [3][32][512] (cross-WG, sc1)
// end = OFF_RH + 98304 = ~12.56 MB

__device__ __forceinline__ unsigned short f2bf(float f) {
    unsigned u = __float_as_uint(f);
    unsigned r = (u + 0x7FFFu + ((u >> 16) & 1u)) >> 16;
    return (unsigned short)r;
}
__device__ __forceinline__ float sigmoidf_(float x) { return 1.0f / (1.0f + __expf(-x)); }

// ---- coherent (LLC-level) access helpers ----
__device__ __forceinline__ short8 load16_coh(const void* p) {
    union { unsigned long long u[2]; short8 s; } r;
    const unsigned long long* q = (const unsigned long long*)p;
    r.u[0] = __hip_atomic_load(q,     __ATOMIC_RELAXED, __HIP_MEMORY_SCOPE_AGENT);
    r.u[1] = __hip_atomic_load(q + 1, __ATOMIC_RELAXED, __HIP_MEMORY_SCOPE_AGENT);
    return r.s;
}
__device__ __forceinline__ void store2_coh(void* p, unsigned short v_) {
    unsigned v32 = v_;
    asm volatile("global_store_short %0, %1, off sc0 sc1" :: "v"(p), "v"(v32) : "memory");
}

// ---------------- pre-pass: converts + init ----------------
__global__ void __launch_bounds__(1024) prep_kernel(
    const float* __restrict__ x, const float* __restrict__ h0,
    const float* __restrict__ W0z, const float* __restrict__ W0r, const float* __restrict__ W0g,
    const float* __restrict__ Wxz, const float* __restrict__ Wxr, const float* __restrict__ Wxg,
    const float* __restrict__ Whz, const float* __restrict__ Whr, const float* __restrict__ Whg,
    const float* __restrict__ Wout, char* __restrict__ ws)
{
    int i = blockIdx.x * 1024 + threadIdx.x;
    unsigned short* xbf = (unsigned short*)(ws + OFF_XBF);
    if (i < B_ * S_ * IN_) xbf[i] = f2bf(x[i]);
    if (i < 65536) {
        ((unsigned short*)(ws + OFF_W0Z))[i]  = f2bf(W0z[i]);
        ((unsigned short*)(ws + OFF_W0R))[i]  = f2bf(W0r[i]);
        ((unsigned short*)(ws + OFF_W0G))[i]  = f2bf(W0g[i]);
        ((unsigned short*)(ws + OFF_WOUT))[i] = f2bf(Wout[i]);
    }
    if (i < 262144) {
        ((unsigned short*)(ws + OFF_WXZ))[i] = f2bf(Wxz[i]);
        ((unsigned short*)(ws + OFF_WXR))[i] = f2bf(Wxr[i]);
        ((unsigned short*)(ws + OFF_WXG))[i] = f2bf(Wxg[i]);
        ((unsigned short*)(ws + OFF_WHZ))[i] = f2bf(Whz[i]);
        ((unsigned short*)(ws + OFF_WHR))[i] = f2bf(Whr[i]);
        ((unsigned short*)(ws + OFF_WHG))[i] = f2bf(Whg[i]);
    }
    if (i < B_ * NL_ * H_) {
        int b = i / (NL_ * H_); int r = i % (NL_ * H_); int j = r / H_; int n = r % H_;
        float v = h0[i];
        ((float*)(ws + OFF_HST))[(j * B_ + b) * H_ + n] = v;
        int par = (j + 1) & 1;  // parity read at layer j's first active step (s=j reads (s-1)&1)
        ((unsigned short*)(ws + OFF_HBF))[((j * 2 + par) * B_ + b) * H_ + n] = f2bf(v);
    }
    if (i < 2048) ((unsigned*)(ws + OFF_BAR))[i] = 0u;   // zero the whole flag region
}

// ---------------- lean fence-free grid barrier ----------------
// Flags packed at 4B stride (104 dwords, 7 lines). Only wave 0 polls: lane i
// checks flags 2i,2i+1 via one 8B relaxed-agent load; wave-local __all loop
// (no per-iteration __syncthreads). Other waves wait at the final barrier.
__device__ __forceinline__ void gbar(unsigned* arrive, int wg, unsigned e, int v, int lane) {
    asm volatile("s_waitcnt vmcnt(0)" ::: "memory");  // this wave's sc1 stores are at LLC
    __syncthreads();                                  // whole WG drained
    if (threadIdx.x == 0)
        __hip_atomic_store(arrive + wg, e, __ATOMIC_RELAXED, __HIP_MEMORY_SCOPE_AGENT);
    if (v == 0) {
        const unsigned long long* fp = (const unsigned long long*)arrive + lane;
        const bool need = lane < (NWG_TOT / 2);
        for (;;) {
            bool ok = true;
            if (need) {
                unsigned long long f = __hip_atomic_load(fp, __ATOMIC_RELAXED, __HIP_MEMORY_SCOPE_AGENT);
                ok = ((unsigned)f >= e) && ((unsigned)(f >> 32) >= e);
            }
            if (__all(ok)) break;
        }
    }
    __syncthreads();
    // no acquire fence: all cross-WG data loads are sc0sc1 (LLC-fresh).
}

// ---------------- the scan: 104 WGs, layer+output pipelined ----------------
__global__ void __launch_bounds__(256, 1) gru_kernel(char* ws,
    const float* __restrict__ b0z, const float* __restrict__ b0r, const float* __restrict__ b0g,
    const float* __restrict__ bxz, const float* __restrict__ bxr, const float* __restrict__ bxg,
    const float* __restrict__ bout, float* __restrict__ out)
{
    const int wg    = blockIdx.x;          // 0..103
    const bool is_out = (wg >= NWG_LAYER);
    const int v     = threadIdx.x >> 6;    // wave 0..3
    const int lane  = threadIdx.x & 63;
    const int btile = v & 1;
    const int khalf = v >> 1;
    const int l15   = lane & 15;
    const int quad  = lane >> 4;
    const int koff  = quad * 8;
    const int arow  = btile * 16 + l15;    // A row (batch)

    unsigned short* hbf_base = (unsigned short*)(ws + OFF_HBF);
    unsigned* arrive = (unsigned*)(ws + OFF_BAR);

    __shared__ float part[4][2][256];

    // ----- layer-WG setup -----
    const int j  = is_out ? 0 : (wg >> 5);     // layer 0..2
    const int nt = wg & 31;                    // n-tile
    const int nrow = nt * 16 + l15;            // feature (layer path)
    const int Tx = (j == 0) ? 4 : 16;          // x-part k-tiles (32 elems each)
    const int T1 = Tx + 16;                    // + h-part
    float bzv = 0.f, brv = 0.f, bgv = 0.f;
    short8 bzc[16], brc[16], bgc[16];
    const short* xbf = (const short*)(ws + OFF_XBF);
    float* hst = (float*)(ws + OFF_HST) + (size_t)j * B_ * H_;
    unsigned short* rh_j = (unsigned short*)(ws + OFF_RH) + (size_t)j * B_ * H_;

    // ----- output-WG setup -----
    const int ont  = wg - NWG_LAYER;           // 0..7
    const int orow = ont * 16 + l15;           // out feature 0..127
    short8 wc[8];
    float bov = 0.f;

    if (!is_out) {
        const float* bz_b = (j == 0) ? b0z : bxz;
        const float* br_b = (j == 0) ? b0r : bxr;
        const float* bg_b = (j == 0) ? b0g : bxg;
        bzv = bz_b[nrow]; brv = br_b[nrow]; bgv = bg_b[nrow];
        const int strx = (j == 0) ? IN_ : H_;
        const short* Wz_x = (const short*)(ws + ((j == 0) ? OFF_W0Z : OFF_WXZ));
        const short* Wr_x = (const short*)(ws + ((j == 0) ? OFF_W0R : OFF_WXR));
        const short* Wg_x = (const short*)(ws + ((j == 0) ? OFF_W0G : OFF_WXG));
        const short* Wz_h = (const short*)(ws + OFF_WHZ);
        const short* Wr_h = (const short*)(ws + OFF_WHR);
        const short* Wg_h = (const short*)(ws + OFF_WHG);
#pragma unroll
        for (int kt = 0; kt < 16; ++kt) {
            short8 z8 = {0, 0, 0, 0, 0, 0, 0, 0};
            bzc[kt] = z8; brc[kt] = z8; bgc[kt] = z8;
            int g = khalf * 16 + kt;
            if (g < T1) {
                if (g < Tx) {
                    long o = (long)nrow * strx + g * 32 + koff;
                    bzc[kt] = *(const short8*)(Wz_x + o);
                    brc[kt] = *(const short8*)(Wr_x + o);
                    bgc[kt] = *(const short8*)(Wg_x + o);
                } else {
                    long o = (long)nrow * H_ + (g - Tx) * 32 + koff;
                    bzc[kt] = *(const short8*)(Wz_h + o);
                    brc[kt] = *(const short8*)(Wr_h + o);
                    bgc[kt] = *(const short8*)(Wg_h + o);
                }
            }
        }
    } else {
        const short* Wo = (const short*)(ws + OFF_WOUT);
        bov = bout[orow];
#pragma unroll
        for (int kt = 0; kt < 8; ++kt) {
            int g = khalf * 8 + kt;   // 16 k-tiles total, split 8/8 across khalf
            wc[kt] = *(const short8*)(Wo + (long)orow * H_ + g * 32 + koff);
        }
    }

    // A-fragment register caches (persist phase1 -> phase2)
    short8 axc[16], ahc[16];

#pragma unroll 1
    for (int s = 0; s < NSTEP; ++s) {
        const int rdpar = (s - 1) & 1;
        const unsigned e1 = 2u * s + 1u, e2 = 2u * s + 2u;

        if (!is_out) {
            // ============ layer phase 1: r gate only ============
            const int t = s - j;
            const bool act = (t >= 0) && (t < S_);
            if (act) {
                const short* hbf_rd = (const short*)(hbf_base + ((size_t)(j * 2 + rdpar)) * B_ * H_);
                const short* inp_rd = (j == 0) ? nullptr
                                    : (const short*)(hbf_base + ((size_t)((j - 1) * 2 + rdpar)) * B_ * H_);
                // ---- batched load burst: all A fragments, one vmcnt pipeline ----
#pragma unroll
                for (int kt = 0; kt < 16; ++kt) {
                    int g = khalf * 16 + kt;
                    if (g < T1) {
                        if (g < Tx) {
                            if (j == 0) axc[kt] = *(const short8*)(xbf + (long)arow * (S_ * IN_) + (long)t * IN_ + g * 32 + koff);
                            else        axc[kt] = load16_coh(inp_rd + (long)arow * H_ + g * 32 + koff);
                        } else {
                            ahc[kt] = load16_coh(hbf_rd + (long)arow * H_ + (g - Tx) * 32 + koff);
                        }
                    }
                }
                floatx4 ar = {0.f, 0.f, 0.f, 0.f};
#pragma unroll
                for (int kt = 0; kt < 16; ++kt) {
                    int g = khalf * 16 + kt;
                    if (g < T1) {
                        short8 af = (g < Tx) ? axc[kt] : ahc[kt];
                        ar = __builtin_amdgcn_mfma_f32_16x16x32_bf16(af, brc[kt], ar, 0, 0, 0);
                    }
                }
#pragma unroll
                for (int i = 0; i < 4; ++i) {
                    int e = (quad * 4 + i) * 16 + l15;
                    part[v][0][e] = ar[i];
                }
            }
            __syncthreads();
            if (act && v < 2) {
                const int btf = v;
#pragma unroll
                for (int i = 0; i < 4; ++i) {
                    int e = (quad * 4 + i) * 16 + l15;
                    float sum = part[btf][0][e] + part[btf + 2][0][e];
                    int bg_ = btf * 16 + quad * 4 + i;
                    float r = sigmoidf_(sum + brv);
                    float h = hst[bg_ * H_ + nrow];
                    store2_coh(rh_j + bg_ * H_ + nrow, f2bf(r * h));
                }
            }
        } else {
            // ============ output stage: out = h2 @ Wout^T + bout ============
            const int t = s - NL_;
            const bool act = (t >= 0);
            if (act) {
                const short* h2 = (const short*)(hbf_base + ((size_t)(2 * 2 + rdpar)) * B_ * H_);
                short8 aoc[8];
#pragma unroll
                for (int kt = 0; kt < 8; ++kt) {
                    int g = khalf * 8 + kt;
                    aoc[kt] = load16_coh(h2 + (long)arow * H_ + g * 32 + koff);
                }
                floatx4 ao = {0.f, 0.f, 0.f, 0.f};
#pragma unroll
                for (int kt = 0; kt < 8; ++kt)
                    ao = __builtin_amdgcn_mfma_f32_16x16x32_bf16(aoc[kt], wc[kt], ao, 0, 0, 0);
#pragma unroll
                for (int i = 0; i < 4; ++i) {
                    int e = (quad * 4 + i) * 16 + l15;
                    part[v][0][e] = ao[i];
                }
            }
            __syncthreads();
            if (act && v < 2) {
                const int btf = v;
#pragma unroll
                for (int i = 0; i < 4; ++i) {
                    int e = (quad * 4 + i) * 16 + l15;
                    float sum = part[btf][0][e] + part[btf + 2][0][e];
                    int bg_ = btf * 16 + quad * 4 + i;
                    out[(long)bg_ * (S_ * OUT_) + (long)t * OUT_ + orow] = sum + bov;
                }
            }
        }
        gbar(arrive, wg, e1, v, lane);

        if (!is_out) {
            // ============ layer phase 2: z + g gates, h update ============
            const int t = s - j;
            const bool act = (t >= 0) && (t < S_);
            if (act) {
                short8 arc[16];
                // only rh fragments are fresh; inp/h frags reused from phase-1 regs
#pragma unroll
                for (int kt = 0; kt < 16; ++kt) {
                    int g = khalf * 16 + kt;
                    if (g >= Tx && g < T1)
                        arc[kt] = load16_coh((const short*)rh_j + (long)arow * H_ + (g - Tx) * 32 + koff);
                }
                floatx4 az = {0.f, 0.f, 0.f, 0.f}, ag = {0.f, 0.f, 0.f, 0.f};
#pragma unroll
                for (int kt = 0; kt < 16; ++kt) {
                    int g = khalf * 16 + kt;
                    if (g < T1) {
                        if (g < Tx) {
                            az = __builtin_amdgcn_mfma_f32_16x16x32_bf16(axc[kt], bzc[kt], az, 0, 0, 0);
                            ag = __builtin_amdgcn_mfma_f32_16x16x32_bf16(axc[kt], bgc[kt], ag, 0, 0, 0);
                        } else {
                            az = __builtin_amdgcn_mfma_f32_16x16x32_bf16(ahc[kt], bzc[kt], az, 0, 0, 0);
                            ag = __builtin_amdgcn_mfma_f32_16x16x32_bf16(arc[kt], bgc[kt], ag, 0, 0, 0);
                        }
                    }
                }
#pragma unroll
                for (int i = 0; i < 4; ++i) {
                    int e = (quad * 4 + i) * 16 + l15;
                    part[v][0][e] = az[i];
                    part[v][1][e] = ag[i];
                }
            }
            __syncthreads();
            if (act && v < 2) {
                const int btf = v;
                unsigned short* hbf_wr = hbf_base + ((size_t)(j * 2 + (s & 1))) * B_ * H_;
#pragma unroll
                for (int i = 0; i < 4; ++i) {
                    int e = (quad * 4 + i) * 16 + l15;
                    float sz = part[btf][0][e] + part[btf + 2][0][e];
                    float sg = part[btf][1][e] + part[btf + 2][1][e];
                    int bg_ = btf * 16 + quad * 4 + i;
                    float z  = sigmoidf_(sz + bzv);
                    float gv = tanhf(sg + bgv);
                    float h  = hst[bg_ * H_ + nrow];
                    float hn = z * h + (1.0f - z) * gv;
                    hst[bg_ * H_ + nrow] = hn;
                    store2_coh(hbf_wr + bg_ * H_ + nrow, f2bf(hn));
                }
            }
        }
        gbar(arrive, wg, e2, v, lane);
    }
}

// ---------------- post-pass: final hidden state ----------------
__global__ void __launch_bounds__(256) tail_kernel(const char* __restrict__ ws, float* __restrict__ out)
{
    int i = blockIdx.x * 256 + threadIdx.x;
    if (i < B_ * NL_ * H_) {
        int b = i / (NL_ * H_); int r = i % (NL_ * H_); int j = r / H_; int n = r % H_;
        out[B_ * S_ * OUT_ + i] = ((const float*)(ws + OFF_HST))[(j * B_ + b) * H_ + n];
    }
}

extern "C" void kernel_launch(void* const* d_in, const int* in_sizes, int n_in,
                              void* d_out, int out_size, void* d_ws, size_t ws_size,
                              hipStream_t stream)
{
    const float* x   = (const float*)d_in[0];
    const float* h0  = (const float*)d_in[1];
    const float* W0z = (const float*)d_in[2];  const float* b0z = (const float*)d_in[3];
    const float* W0r = (const float*)d_in[4];  const float* b0r = (const float*)d_in[5];
    const float* W0g = (const float*)d_in[6];  const float* b0g = (const float*)d_in[7];
    const float* Wxz = (const float*)d_in[8];  const float* bxz = (const float*)d_in[9];
    const float* Wxr = (const float*)d_in[10]; const float* bxr = (const float*)d_in[11];
    const float* Wxg = (const float*)d_in[12]; const float* bxg = (const float*)d_in[13];
    const float* Whz = (const float*)d_in[14];
    const float* Whr = (const float*)d_in[15];
    const float* Whg = (const float*)d_in[16];
    const float* Wout = (const float*)d_in[17]; const float* bout = (const float*)d_in[18];
    char* ws = (char*)d_ws;
    float* out = (float*)d_out;

    prep_kernel<<<dim3(4096), dim3(1024), 0, stream>>>(
        x, h0, W0z, W0r, W0g, Wxz, Wxr, Wxg, Whz, Whr, Whg, Wout, ws);

    gru_kernel<<<dim3(NWG_TOT), dim3(256), 0, stream>>>(
        ws, b0z, b0r, b0g, bxz, bxr, bxg, bout, out);

    tail_kernel<<<dim3(192), dim3(256), 0, stream>>>((const char*)ws, out);
}

// Round 6
// 14420.341 us; speedup vs baseline: 1.7128x; 1.7128x over previous
//
#include <hip/hip_runtime.h>
#include <cstdint>
#include <cstddef>

// ---------------- problem constants ----------------
#define B_   32
#define S_   1024
#define IN_  128
#define H_   512
#define OUT_ 128
#define NL_  3
#define NWG_LAYER 96            // 3 layers x 32 n-tiles
#define NWG_TOT   104           // + 8 output-projection WGs
#define NSTEP (S_ + NL_)        // 1027 pipeline steps

typedef __attribute__((ext_vector_type(8))) short short8;   // 8 bf16 (4 VGPRs)
typedef __attribute__((ext_vector_type(4))) float floatx4;  // MFMA C/D
typedef __attribute__((ext_vector_type(2))) unsigned uint2v;

// ---------------- workspace layout (bytes); total ~12.6 MB ----------------
constexpr size_t OFF_BAR  = 0;                        // arrive[104] packed 4B (7 lines)
constexpr size_t OFF_W0Z  = 8192;                     // 512x128 bf16
constexpr size_t OFF_W0R  = OFF_W0Z + 131072;
constexpr size_t OFF_W0G  = OFF_W0R + 131072;
constexpr size_t OFF_WXZ  = OFF_W0G + 131072;         // 512x512 bf16 each
constexpr size_t OFF_WXR  = OFF_WXZ + 524288;
constexpr size_t OFF_WXG  = OFF_WXR + 524288;
constexpr size_t OFF_WHZ  = OFF_WXG + 524288;
constexpr size_t OFF_WHR  = OFF_WHZ + 524288;
constexpr size_t OFF_WHG  = OFF_WHR + 524288;
constexpr size_t OFF_WOUT = OFF_WHG + 524288;         // 128x512 bf16
constexpr size_t OFF_XBF  = OFF_WOUT + 131072;        // x bf16 [32][1024][128]
constexpr size_t OFF_HST  = OFF_XBF + 8388608;        // f32 h state [3][32][512] (WG-private strips)
constexpr size_t OFF_HBF  = OFF_HST + 196608;         // bf16 h double-buf [3][2][32][512] (cross-WG, sc1)
constexpr size_t OFF_RH   = OFF_HBF + 196608;         // bf16 r*h [3][32][512] (cross-WG, sc1)
// end = OFF_RH + 98304 = ~12.56 MB

__device__ __forceinline__ unsigned short f2bf(float f) {
    unsigned u = __float_as_uint(f);
    unsigned r = (u + 0x7FFFu + ((u >> 16) & 1u)) >> 16;
    return (unsigned short)r;
}
__device__ __forceinline__ float sigmoidf_(float x) { return 1.0f / (1.0f + __expf(-x)); }

// ---- coherent (LLC-level) access helpers ----
__device__ __forceinline__ short8 load16_coh(const void* p) {
    union { unsigned long long u[2]; short8 s; } r;
    const unsigned long long* q = (const unsigned long long*)p;
    r.u[0] = __hip_atomic_load(q,     __ATOMIC_RELAXED, __HIP_MEMORY_SCOPE_AGENT);
    r.u[1] = __hip_atomic_load(q + 1, __ATOMIC_RELAXED, __HIP_MEMORY_SCOPE_AGENT);
    return r.s;
}
// 8B packed write-through to LLC (one dwordx2 transaction)
__device__ __forceinline__ void store8_coh(void* p, unsigned lo, unsigned hi) {
    uint2v u; u.x = lo; u.y = hi;
    asm volatile("global_store_dwordx2 %0, %1, off sc0 sc1" :: "v"(p), "v"(u) : "memory");
}

// ---------------- pre-pass: converts + init ----------------
__global__ void __launch_bounds__(1024) prep_kernel(
    const float* __restrict__ x, const float* __restrict__ h0,
    const float* __restrict__ W0z, const float* __restrict__ W0r, const float* __restrict__ W0g,
    const float* __restrict__ Wxz, const float* __restrict__ Wxr, const float* __restrict__ Wxg,
    const float* __restrict__ Whz, const float* __restrict__ Whr, const float* __restrict__ Whg,
    const float* __restrict__ Wout, char* __restrict__ ws)
{
    int i = blockIdx.x * 1024 + threadIdx.x;
    unsigned short* xbf = (unsigned short*)(ws + OFF_XBF);
    if (i < B_ * S_ * IN_) xbf[i] = f2bf(x[i]);
    if (i < 65536) {
        ((unsigned short*)(ws + OFF_W0Z))[i]  = f2bf(W0z[i]);
        ((unsigned short*)(ws + OFF_W0R))[i]  = f2bf(W0r[i]);
        ((unsigned short*)(ws + OFF_W0G))[i]  = f2bf(W0g[i]);
        ((unsigned short*)(ws + OFF_WOUT))[i] = f2bf(Wout[i]);
    }
    if (i < 262144) {
        ((unsigned short*)(ws + OFF_WXZ))[i] = f2bf(Wxz[i]);
        ((unsigned short*)(ws + OFF_WXR))[i] = f2bf(Wxr[i]);
        ((unsigned short*)(ws + OFF_WXG))[i] = f2bf(Wxg[i]);
        ((unsigned short*)(ws + OFF_WHZ))[i] = f2bf(Whz[i]);
        ((unsigned short*)(ws + OFF_WHR))[i] = f2bf(Whr[i]);
        ((unsigned short*)(ws + OFF_WHG))[i] = f2bf(Whg[i]);
    }
    if (i < B_ * NL_ * H_) {
        int b = i / (NL_ * H_); int r = i % (NL_ * H_); int j = r / H_; int n = r % H_;
        float v = h0[i];
        ((float*)(ws + OFF_HST))[(j * B_ + b) * H_ + n] = v;
        int par = (j + 1) & 1;  // parity read at layer j's first active step (s=j reads (s-1)&1)
        ((unsigned short*)(ws + OFF_HBF))[((j * 2 + par) * B_ + b) * H_ + n] = f2bf(v);
    }
    if (i < 2048) ((unsigned*)(ws + OFF_BAR))[i] = 0u;   // zero the whole flag region
}

// ---------------- lean fence-free grid barrier (unchanged from R4) ----------------
__device__ __forceinline__ void gbar(unsigned* arrive, int wg, unsigned e, int v, int lane) {
    asm volatile("s_waitcnt vmcnt(0)" ::: "memory");  // this wave's sc1 stores are at LLC
    __syncthreads();                                  // whole WG drained
    if (threadIdx.x == 0)
        __hip_atomic_store(arrive + wg, e, __ATOMIC_RELAXED, __HIP_MEMORY_SCOPE_AGENT);
    if (v == 0) {
        const unsigned long long* fp = (const unsigned long long*)arrive + lane;
        const bool need = lane < (NWG_TOT / 2);
        for (;;) {
            bool ok = true;
            if (need) {
                unsigned long long f = __hip_atomic_load(fp, __ATOMIC_RELAXED, __HIP_MEMORY_SCOPE_AGENT);
                ok = ((unsigned)f >= e) && ((unsigned)(f >> 32) >= e);
            }
            if (__all(ok)) break;
        }
    }
    __syncthreads();
}

// ---------------- the scan: 104 WGs, layer+output pipelined ----------------
// Per wave: z,g weight frags in VGPRs (128); r weight frags in LDS (32 KB);
// one A-fragment array (64 VGPRs) reused phase1->phase2.
__global__ void __launch_bounds__(256, 1) gru_kernel(char* ws,
    const float* __restrict__ b0z, const float* __restrict__ b0r, const float* __restrict__ b0g,
    const float* __restrict__ bxz, const float* __restrict__ bxr, const float* __restrict__ bxg,
    const float* __restrict__ bout, float* __restrict__ out)
{
    const int wg    = blockIdx.x;          // 0..103
    const bool is_out = (wg >= NWG_LAYER);
    const int tid   = threadIdx.x;
    const int v     = tid >> 6;            // wave 0..3
    const int lane  = tid & 63;
    const int btile = v & 1;
    const int khalf = v >> 1;
    const int l15   = lane & 15;
    const int quad  = lane >> 4;
    const int koff  = quad * 8;
    const int arow  = btile * 16 + l15;    // A row (batch)

    unsigned short* hbf_base = (unsigned short*)(ws + OFF_HBF);
    unsigned* arrive = (unsigned*)(ws + OFF_BAR);

    __shared__ float part[4][2][256];          // 8 KB
    __shared__ short8 wrl[2][16][64];          // 32 KB: r-gate weight frags [khalf][kt][lane]

    // ----- layer-WG setup -----
    const int j  = is_out ? 0 : (wg >> 5);     // layer 0..2
    const int nt = wg & 31;                    // n-tile
    const int nrow = nt * 16 + l15;            // feature (layer path)
    const int Tx = (j == 0) ? 4 : 16;          // x-part k-tiles (32 elems each)
    const int T1 = Tx + 16;                    // + h-part
    short8 wzc[16], wgc[16];
    const short* xbf = (const short*)(ws + OFF_XBF);
    float* hst = (float*)(ws + OFF_HST) + (size_t)j * B_ * H_;
    unsigned short* rh_j = (unsigned short*)(ws + OFF_RH) + (size_t)j * B_ * H_;

    // ----- output-WG setup -----
    const int ont  = wg - NWG_LAYER;           // 0..7
    short8 wc[8];

    // ----- reducer-thread setup (tid<128): owns (b = tid>>2, 4 consecutive n) -----
    const int rb  = tid >> 2;                  // batch row 0..31
    const int bq  = rb >> 4;                   // btile of row
    const int bl  = rb & 15;                   // row within tile
    const int rnl = (tid & 3) * 4;             // n-offset within 16-wide tile
    float4 brv4 = {0,0,0,0}, bzv4 = {0,0,0,0}, bgv4 = {0,0,0,0}, bov4 = {0,0,0,0};

    if (!is_out) {
        const float* bz_b = (j == 0) ? b0z : bxz;
        const float* br_b = (j == 0) ? b0r : bxr;
        const float* bg_b = (j == 0) ? b0g : bxg;
        if (tid < 128) {
            bzv4 = *(const float4*)(bz_b + nt * 16 + rnl);
            brv4 = *(const float4*)(br_b + nt * 16 + rnl);
            bgv4 = *(const float4*)(bg_b + nt * 16 + rnl);
        }
        const int strx = (j == 0) ? IN_ : H_;
        const short* Wz_x = (const short*)(ws + ((j == 0) ? OFF_W0Z : OFF_WXZ));
        const short* Wr_x = (const short*)(ws + ((j == 0) ? OFF_W0R : OFF_WXR));
        const short* Wg_x = (const short*)(ws + ((j == 0) ? OFF_W0G : OFF_WXG));
        const short* Wz_h = (const short*)(ws + OFF_WHZ);
        const short* Wr_h = (const short*)(ws + OFF_WHR);
        const short* Wg_h = (const short*)(ws + OFF_WHG);
#pragma unroll
        for (int kt = 0; kt < 16; ++kt) {
            int g = khalf * 16 + kt;
            if (g < T1) {
                if (g < Tx) {
                    long o = (long)nrow * strx + g * 32 + koff;
                    wzc[kt] = *(const short8*)(Wz_x + o);
                    wgc[kt] = *(const short8*)(Wg_x + o);
                    wrl[khalf][kt][lane] = *(const short8*)(Wr_x + o);
                } else {
                    long o = (long)nrow * H_ + (g - Tx) * 32 + koff;
                    wzc[kt] = *(const short8*)(Wz_h + o);
                    wgc[kt] = *(const short8*)(Wg_h + o);
                    wrl[khalf][kt][lane] = *(const short8*)(Wr_h + o);
                }
            }
        }
    } else {
        const short* Wo = (const short*)(ws + OFF_WOUT);
        if (tid < 128) bov4 = *(const float4*)(bout + ont * 16 + rnl);
#pragma unroll
        for (int kt = 0; kt < 8; ++kt) {
            int g = khalf * 8 + kt;
            wc[kt] = *(const short8*)(Wo + (long)(ont * 16 + l15) * H_ + g * 32 + koff);
        }
    }
    __syncthreads();   // wrl visible to all waves

    short8 afrag[16];          // per-wave A fragments (reused phase1 -> phase2)
    float zacc[4];             // reducer: raw z sums carried phase1 -> phase2
    float hv[4];               // reducer: h(t-1) carried phase1 -> phase2

#pragma unroll 1
    for (int s = 0; s < NSTEP; ++s) {
        const int rdpar = (s - 1) & 1;
        const unsigned e1 = 2u * s + 1u, e2 = 2u * s + 2u;

        if (!is_out) {
            // ============ phase 1: z + r matmuls, rh production ============
            const int t = s - j;
            const bool act = (t >= 0) && (t < S_);
            if (act) {
                const short* hbf_rd = (const short*)(hbf_base + ((size_t)(j * 2 + rdpar)) * B_ * H_);
                const short* inp_rd = (j == 0) ? nullptr
                                    : (const short*)(hbf_base + ((size_t)((j - 1) * 2 + rdpar)) * B_ * H_);
                // batched A-fragment load burst (one vmcnt pipeline)
#pragma unroll
                for (int kt = 0; kt < 16; ++kt) {
                    int g = khalf * 16 + kt;
                    if (g < T1) {
                        if (g < Tx) {
                            if (j == 0) afrag[kt] = *(const short8*)(xbf + (long)arow * (S_ * IN_) + (long)t * IN_ + g * 32 + koff);
                            else        afrag[kt] = load16_coh(inp_rd + (long)arow * H_ + g * 32 + koff);
                        } else {
                            afrag[kt] = load16_coh(hbf_rd + (long)arow * H_ + (g - Tx) * 32 + koff);
                        }
                    }
                }
                floatx4 az = {0.f, 0.f, 0.f, 0.f}, ar = {0.f, 0.f, 0.f, 0.f};
#pragma unroll
                for (int kt = 0; kt < 16; ++kt) {
                    int g = khalf * 16 + kt;
                    if (g < T1) {
                        short8 wr = wrl[khalf][kt][lane];
                        az = __builtin_amdgcn_mfma_f32_16x16x32_bf16(afrag[kt], wzc[kt], az, 0, 0, 0);
                        ar = __builtin_amdgcn_mfma_f32_16x16x32_bf16(afrag[kt], wr, ar, 0, 0, 0);
                    }
                }
#pragma unroll
                for (int i = 0; i < 4; ++i) {
                    int e = (quad * 4 + i) * 16 + l15;
                    part[v][0][e] = az[i];
                    part[v][1][e] = ar[i];
                }
            }
            __syncthreads();
            if (act && tid < 128) {
                float4 h4 = *(const float4*)(hst + rb * H_ + nt * 16 + rnl);
                unsigned lo = 0, hi = 0;
#pragma unroll
                for (int m = 0; m < 4; ++m) {
                    int e = bl * 16 + rnl + m;
                    float zs = part[bq][0][e] + part[bq + 2][0][e];
                    float rs = part[bq][1][e] + part[bq + 2][1][e];
                    zacc[m] = zs;
                    hv[m] = h4[m];
                    float r = sigmoidf_(rs + brv4[m]);
                    unsigned p = (unsigned)f2bf(r * h4[m]) << (16 * (m & 1));
                    if (m < 2) lo |= p; else hi |= p;
                }
                store8_coh(rh_j + rb * H_ + nt * 16 + rnl, lo, hi);
            }
        } else {
            // ============ output stage: out = h2 @ Wout^T + bout ============
            const int t = s - NL_;
            const bool act = (t >= 0);
            if (act) {
                const short* h2 = (const short*)(hbf_base + ((size_t)(2 * 2 + rdpar)) * B_ * H_);
                short8 aoc[8];
#pragma unroll
                for (int kt = 0; kt < 8; ++kt) {
                    int g = khalf * 8 + kt;
                    aoc[kt] = load16_coh(h2 + (long)arow * H_ + g * 32 + koff);
                }
                floatx4 ao = {0.f, 0.f, 0.f, 0.f};
#pragma unroll
                for (int kt = 0; kt < 8; ++kt)
                    ao = __builtin_amdgcn_mfma_f32_16x16x32_bf16(aoc[kt], wc[kt], ao, 0, 0, 0);
#pragma unroll
                for (int i = 0; i < 4; ++i) {
                    int e = (quad * 4 + i) * 16 + l15;
                    part[v][0][e] = ao[i];
                }
            }
            __syncthreads();
            if (act && tid < 128) {
                float4 o4;
#pragma unroll
                for (int m = 0; m < 4; ++m) {
                    int e = bl * 16 + rnl + m;
                    o4[m] = part[bq][0][e] + part[bq + 2][0][e] + bov4[m];
                }
                *(float4*)(out + (long)rb * (S_ * OUT_) + (long)t * OUT_ + ont * 16 + rnl) = o4;
            }
        }
        gbar(arrive, wg, e1, v, lane);

        if (!is_out) {
            // ============ phase 2: g matmul (inp frags reused; h frags -> rh), h update ============
            const int t = s - j;
            const bool act = (t >= 0) && (t < S_);
            if (act) {
#pragma unroll
                for (int kt = 0; kt < 16; ++kt) {
                    int g = khalf * 16 + kt;
                    if (g >= Tx && g < T1)
                        afrag[kt] = load16_coh((const short*)rh_j + (long)arow * H_ + (g - Tx) * 32 + koff);
                }
                floatx4 ag = {0.f, 0.f, 0.f, 0.f};
#pragma unroll
                for (int kt = 0; kt < 16; ++kt) {
                    int g = khalf * 16 + kt;
                    if (g < T1)
                        ag = __builtin_amdgcn_mfma_f32_16x16x32_bf16(afrag[kt], wgc[kt], ag, 0, 0, 0);
                }
#pragma unroll
                for (int i = 0; i < 4; ++i) {
                    int e = (quad * 4 + i) * 16 + l15;
                    part[v][0][e] = ag[i];
                }
            }
            __syncthreads();
            if (act && tid < 128) {
                unsigned short* hbf_wr = hbf_base + ((size_t)(j * 2 + (s & 1))) * B_ * H_;
                float4 h4n;
                unsigned lo = 0, hi = 0;
#pragma unroll
                for (int m = 0; m < 4; ++m) {
                    int e = bl * 16 + rnl + m;
                    float gs = part[bq][0][e] + part[bq + 2][0][e];
                    float gv = tanhf(gs + bgv4[m]);
                    float z  = sigmoidf_(zacc[m] + bzv4[m]);
                    float hn = z * hv[m] + (1.0f - z) * gv;
                    h4n[m] = hn;
                    unsigned p = (unsigned)f2bf(hn) << (16 * (m & 1));
                    if (m < 2) lo |= p; else hi |= p;
                }
                *(float4*)(hst + rb * H_ + nt * 16 + rnl) = h4n;       // WG-private, cached
                store8_coh(hbf_wr + rb * H_ + nt * 16 + rnl, lo, hi);  // cross-WG
            }
        }
        gbar(arrive, wg, e2, v, lane);
    }
}

// ---------------- post-pass: final hidden state ----------------
__global__ void __launch_bounds__(256) tail_kernel(const char* __restrict__ ws, float* __restrict__ out)
{
    int i = blockIdx.x * 256 + threadIdx.x;
    if (i < B_ * NL_ * H_) {
        int b = i / (NL_ * H_); int r = i % (NL_ * H_); int j = r / H_; int n = r % H_;
        out[B_ * S_ * OUT_ + i] = ((const float*)(ws + OFF_HST))[(j * B_ + b) * H_ + n];
    }
}

extern "C" void kernel_launch(void* const* d_in, const int* in_sizes, int n_in,
                              void* d_out, int out_size, void* d_ws, size_t ws_size,
                              hipStream_t stream)
{
    const float* x   = (const float*)d_in[0];
    const float* h0  = (const float*)d_in[1];
    const float* W0z = (const float*)d_in[2];  const float* b0z = (const float*)d_in[3];
    const float* W0r = (const float*)d_in[4];  const float* b0r = (const float*)d_in[5];
    const float* W0g = (const float*)d_in[6];  const float* b0g = (const float*)d_in[7];
    const float* Wxz = (const float*)d_in[8];  const float* bxz = (const float*)d_in[9];
    const float* Wxr = (const float*)d_in[10]; const float* bxr = (const float*)d_in[11];
    const float* Wxg = (const float*)d_in[12]; const float* bxg = (const float*)d_in[13];
    const float* Whz = (const float*)d_in[14];
    const float* Whr = (const float*)d_in[15];
    const float* Whg = (const float*)d_in[16];
    const float* Wout = (const float*)d_in[17]; const float* bout = (const float*)d_in[18];
    char* ws = (char*)d_ws;
    float* out = (float*)d_out;

    prep_kernel<<<dim3(4096), dim3(1024), 0, stream>>>(
        x, h0, W0z, W0r, W0g, Wxz, Wxr, Wxg, Whz, Whr, Whg, Wout, ws);

    gru_kernel<<<dim3(NWG_TOT), dim3(256), 0, stream>>>(
        ws, b0z, b0r, b0g, bxz, bxr, bxg, bout, out);

    tail_kernel<<<dim3(192), dim3(256), 0, stream>>>((const char*)ws, out);
}

// Round 7
// 8144.215 us; speedup vs baseline: 3.0327x; 1.7706x over previous
//
#include <hip/hip_runtime.h>
#include <cstdint>
#include <cstddef>

// ---------------- problem constants ----------------
#define B_   32
#define S_   1024
#define IN_  128
#define H_   512
#define OUT_ 128
#define NL_  3

typedef __attribute__((ext_vector_type(8))) short short8;   // 8 bf16 (4 VGPRs)
typedef __attribute__((ext_vector_type(4))) float floatx4;  // MFMA C/D
typedef __attribute__((ext_vector_type(2))) unsigned uint2v;

// ---------------- workspace layout (bytes) ----------------
// flags (each 32-flag group on its own 128B):
constexpr size_t OFF_CLAIM = 0;        // 8 uints
constexpr size_t OFF_P1L   = 128;      // [3][32] phase1-done, local (L2)
constexpr size_t OFF_P2L   = 512;      // [3][32] phase2-done, local (L2)
constexpr size_t OFF_P1R   = 896;      // [3][32] phase1-done, remote (sc1)
constexpr size_t OFF_P2R   = 1280;     // [3][32] phase2-done, remote (sc1)
constexpr size_t OFF_PO    = 1664;     // [32] out-done (8 real + 24 padded huge)
constexpr size_t OFF_W0Z  = 8192;                     // 512x128 bf16
constexpr size_t OFF_W0R  = OFF_W0Z + 131072;
constexpr size_t OFF_W0G  = OFF_W0R + 131072;
constexpr size_t OFF_WXZ  = OFF_W0G + 131072;         // 512x512 bf16 each
constexpr size_t OFF_WXR  = OFF_WXZ + 524288;
constexpr size_t OFF_WXG  = OFF_WXR + 524288;
constexpr size_t OFF_WHZ  = OFF_WXG + 524288;
constexpr size_t OFF_WHR  = OFF_WHZ + 524288;
constexpr size_t OFF_WHG  = OFF_WHR + 524288;
constexpr size_t OFF_WOUT = OFF_WHG + 524288;         // 128x512 bf16
constexpr size_t OFF_XBF  = OFF_WOUT + 131072;        // x bf16 [32][1024][128]
constexpr size_t OFF_HST  = OFF_XBF + 8388608;        // f32 h state [3][32][512] (WG-private)
constexpr size_t OFF_HLOC = OFF_HST + 196608;         // bf16 h [3][4slots][32][512] intra-XCD (L2)
constexpr size_t OFF_HREM = OFF_HLOC + 393216;        // bf16 h [3][4slots][32][512] cross-XCD (sc1)
constexpr size_t OFF_RH   = OFF_HREM + 393216;        // bf16 r*h [3][32][512] intra-XCD (L2)
// end = OFF_RH + 98304 = 13,148,160 bytes

__device__ __forceinline__ unsigned short f2bf(float f) {
    unsigned u = __float_as_uint(f);
    unsigned r = (u + 0x7FFFu + ((u >> 16) & 1u)) >> 16;
    return (unsigned short)r;
}
__device__ __forceinline__ float sigmoidf_(float x) { return 1.0f / (1.0f + __expf(-x)); }

// ---- cross-XCD (LLC) helpers — proven r4-r6 recipe ----
__device__ __forceinline__ short8 load16_coh(const void* p) {
    union { unsigned long long u[2]; short8 s; } r;
    const unsigned long long* q = (const unsigned long long*)p;
    r.u[0] = __hip_atomic_load(q,     __ATOMIC_RELAXED, __HIP_MEMORY_SCOPE_AGENT);
    r.u[1] = __hip_atomic_load(q + 1, __ATOMIC_RELAXED, __HIP_MEMORY_SCOPE_AGENT);
    return r.s;
}
__device__ __forceinline__ void store8_coh(void* p, unsigned lo, unsigned hi) {
    uint2v u; u.x = lo; u.y = hi;
    asm volatile("global_store_dwordx2 %0, %1, off sc0 sc1" :: "v"(p), "v"(u) : "memory");
}

#define VDRAIN() asm volatile("s_waitcnt vmcnt(0)" ::: "memory")

// ---- flag helpers ----
__device__ __forceinline__ unsigned wave_min32_bcast(unsigned f) {
#pragma unroll
    for (int off = 1; off < 32; off <<= 1) {
        unsigned o = (unsigned)__shfl_xor((int)f, off, 64);
        f = (o < f) ? o : f;
    }
    return (unsigned)__shfl((int)f, 0, 64);
}
// intra-XCD poll (nt loads: L2-served, never L1-allocated)
__device__ __forceinline__ unsigned poll_loc32(const unsigned* flags, unsigned thr, int skip, int lane) {
    const unsigned* p = flags + (lane & 31);
    unsigned f;
    for (;;) {
        f = __builtin_nontemporal_load(p);
        if ((lane & 31) == skip) f = 0xFFFFFFFFu;
        if (__all((int)(f >= thr))) break;
        asm volatile("s_sleep 1" ::: "memory");
    }
    return wave_min32_bcast(f);
}
// cross-XCD poll
__device__ __forceinline__ unsigned poll_rem32(const unsigned* flags, unsigned thr, int lane) {
    const unsigned* p = flags + (lane & 31);
    unsigned f;
    for (;;) {
        f = __hip_atomic_load(p, __ATOMIC_RELAXED, __HIP_MEMORY_SCOPE_AGENT);
        if (__all((int)(f >= thr))) break;
        asm volatile("s_sleep 2" ::: "memory");
    }
    return wave_min32_bcast(f);
}
__device__ __forceinline__ void st_flag_loc(unsigned* p, unsigned v) { __builtin_nontemporal_store(v, p); }
__device__ __forceinline__ void st_flag_rem(unsigned* p, unsigned v) {
    __hip_atomic_store(p, v, __ATOMIC_RELAXED, __HIP_MEMORY_SCOPE_AGENT);
}

// ---------------- pre-pass: converts + init ----------------
__global__ void __launch_bounds__(1024) prep_kernel(
    const float* __restrict__ x, const float* __restrict__ h0,
    const float* __restrict__ W0z, const float* __restrict__ W0r, const float* __restrict__ W0g,
    const float* __restrict__ Wxz, const float* __restrict__ Wxr, const float* __restrict__ Wxg,
    const float* __restrict__ Whz, const float* __restrict__ Whr, const float* __restrict__ Whg,
    const float* __restrict__ Wout, char* __restrict__ ws)
{
    int i = blockIdx.x * 1024 + threadIdx.x;
    unsigned short* xbf = (unsigned short*)(ws + OFF_XBF);
    if (i < B_ * S_ * IN_) xbf[i] = f2bf(x[i]);
    if (i < 65536) {
        ((unsigned short*)(ws + OFF_W0Z))[i]  = f2bf(W0z[i]);
        ((unsigned short*)(ws + OFF_W0R))[i]  = f2bf(W0r[i]);
        ((unsigned short*)(ws + OFF_W0G))[i]  = f2bf(W0g[i]);
        ((unsigned short*)(ws + OFF_WOUT))[i] = f2bf(Wout[i]);
    }
    if (i < 262144) {
        ((unsigned short*)(ws + OFF_WXZ))[i] = f2bf(Wxz[i]);
        ((unsigned short*)(ws + OFF_WXR))[i] = f2bf(Wxr[i]);
        ((unsigned short*)(ws + OFF_WXG))[i] = f2bf(Wxg[i]);
        ((unsigned short*)(ws + OFF_WHZ))[i] = f2bf(Whz[i]);
        ((unsigned short*)(ws + OFF_WHR))[i] = f2bf(Whr[i]);
        ((unsigned short*)(ws + OFF_WHG))[i] = f2bf(Whg[i]);
    }
    if (i < B_ * NL_ * H_) {
        int b = i / (NL_ * H_); int r = i % (NL_ * H_); int j = r / H_; int n = r % H_;
        float v = h0[i];
        ((float*)(ws + OFF_HST))[(j * B_ + b) * H_ + n] = v;
        // phase1 t=0 reads hloc slot (0-1)&3 = 3
        ((unsigned short*)(ws + OFF_HLOC))[((j * 4 + 3) * B_ + b) * H_ + n] = f2bf(v);
    }
    if (i < 448) {   // zero claim + all flag groups; pad PO slots 8..31 with huge
        unsigned v = 0u;
        int rel = i - (int)(OFF_PO / 4);
        if (rel >= 8 && rel < 32) v = 0xFFFFFFFFu;
        ((unsigned*)ws)[i] = v;
    }
}

// ---------------- the scan: XCD-claimed roles, p2p flags ----------------
__global__ void __launch_bounds__(256, 1) gru_kernel(char* ws,
    const float* __restrict__ b0z, const float* __restrict__ b0r, const float* __restrict__ b0g,
    const float* __restrict__ bxz, const float* __restrict__ bxr, const float* __restrict__ bxg,
    const float* __restrict__ bout, float* __restrict__ out)
{
    // ---- role claim: layer j on XCD j (32 WGs), out on XCD 3 (8 WGs) ----
    __shared__ int role_s;
    if (threadIdx.x == 0) {
        int xcc;
        asm volatile("s_getreg_b32 %0, hwreg(HW_REG_XCC_ID, 0, 32)" : "=s"(xcc));
        xcc &= 7;
        int role = -1;
        unsigned slot = atomicAdd((unsigned*)(ws + OFF_CLAIM) + xcc, 1u);
        if (xcc < 3)       { if (slot < 32) role = xcc * 32 + (int)slot; }
        else if (xcc == 3) { if (slot < 8)  role = 96 + (int)slot; }
        role_s = role;
    }
    __syncthreads();
    const int role = role_s;
    if (role < 0) return;

    const bool is_out = (role >= 96);
    const int tid   = threadIdx.x;
    const int v     = tid >> 6;
    const int lane  = tid & 63;
    const int btile = v & 1;
    const int khalf = v >> 1;
    const int l15   = lane & 15;
    const int quad  = lane >> 4;
    const int koff  = quad * 8;
    const int arow  = btile * 16 + l15;

    __shared__ float part[4][2][256];          // 8 KB
    __shared__ short8 wrl[2][16][64];          // 32 KB r-gate weight frags

    // ----- layer setup -----
    const int j  = is_out ? 0 : (role >> 5);
    const int nt = role & 31;
    const int nrow = nt * 16 + l15;
    const int Tx = (j == 0) ? 4 : 16;
    const int T1 = Tx + 16;
    short8 wzc[16], wgc[16];
    const short* xbf = (const short*)(ws + OFF_XBF);
    float* hst = (float*)(ws + OFF_HST) + (size_t)j * B_ * H_;
    unsigned short* hloc = (unsigned short*)(ws + OFF_HLOC);
    unsigned short* hrem = (unsigned short*)(ws + OFF_HREM);
    unsigned short* rh_j = (unsigned short*)(ws + OFF_RH) + (size_t)j * B_ * H_;

    unsigned* p1l = (unsigned*)(ws + OFF_P1L) + j * 32;
    unsigned* p2l = (unsigned*)(ws + OFF_P2L) + j * 32;
    unsigned* p1r_self = (unsigned*)(ws + OFF_P1R) + j * 32;
    unsigned* p2r_self = (unsigned*)(ws + OFF_P2R) + j * 32;
    unsigned* p2r_low  = (unsigned*)(ws + OFF_P2R) + (j - 1) * 32;   // j>=1 only
    unsigned* warfl    = (j < 2) ? (unsigned*)(ws + OFF_P1R) + (j + 1) * 32
                                 : (unsigned*)(ws + OFF_PO);
    unsigned* p2r2 = (unsigned*)(ws + OFF_P2R) + 2 * 32;
    unsigned* pofl = (unsigned*)(ws + OFF_PO);

    // ----- out setup -----
    const int ont = role - 96;
    short8 wc[8];

    // ----- reducer mapping (tid<128): owns (b = tid>>2, 4 consecutive n) -----
    const int rb  = tid >> 2;
    const int bq  = rb >> 4;
    const int bl  = rb & 15;
    const int rnl = (tid & 3) * 4;
    float4 brv4 = {0,0,0,0}, bzv4 = {0,0,0,0}, bgv4 = {0,0,0,0}, bov4 = {0,0,0,0};

    if (!is_out) {
        const float* bz_b = (j == 0) ? b0z : bxz;
        const float* br_b = (j == 0) ? b0r : bxr;
        const float* bg_b = (j == 0) ? b0g : bxg;
        if (tid < 128) {
            bzv4 = *(const float4*)(bz_b + nt * 16 + rnl);
            brv4 = *(const float4*)(br_b + nt * 16 + rnl);
            bgv4 = *(const float4*)(bg_b + nt * 16 + rnl);
        }
        const int strx = (j == 0) ? IN_ : H_;
        const short* Wz_x = (const short*)(ws + ((j == 0) ? OFF_W0Z : OFF_WXZ));
        const short* Wr_x = (const short*)(ws + ((j == 0) ? OFF_W0R : OFF_WXR));
        const short* Wg_x = (const short*)(ws + ((j == 0) ? OFF_W0G : OFF_WXG));
        const short* Wz_h = (const short*)(ws + OFF_WHZ);
        const short* Wr_h = (const short*)(ws + OFF_WHR);
        const short* Wg_h = (const short*)(ws + OFF_WHG);
#pragma unroll
        for (int kt = 0; kt < 16; ++kt) {
            int g = khalf * 16 + kt;
            if (g < T1) {
                if (g < Tx) {
                    long o = (long)nrow * strx + g * 32 + koff;
                    wzc[kt] = *(const short8*)(Wz_x + o);
                    wgc[kt] = *(const short8*)(Wg_x + o);
                    wrl[khalf][kt][lane] = *(const short8*)(Wr_x + o);
                } else {
                    long o = (long)nrow * H_ + (g - Tx) * 32 + koff;
                    wzc[kt] = *(const short8*)(Wz_h + o);
                    wgc[kt] = *(const short8*)(Wg_h + o);
                    wrl[khalf][kt][lane] = *(const short8*)(Wr_h + o);
                }
            }
        }
    } else {
        const short* Wo = (const short*)(ws + OFF_WOUT);
        if (tid < 128) bov4 = *(const float4*)(bout + ont * 16 + rnl);
#pragma unroll
        for (int kt = 0; kt < 8; ++kt) {
            int g = khalf * 8 + kt;
            wc[kt] = *(const short8*)(Wo + (long)(ont * 16 + l15) * H_ + g * 32 + koff);
        }
    }
    __syncthreads();

    if (!is_out) {
        short8 afrag[16];
        float zacc[4], hv[4];
        unsigned defer_lo = 0, defer_hi = 0;
        unsigned memoA = 0, memoB = 0, memoC = 0, memoD = 0;

#pragma unroll 1
        for (int t = 0; t < S_; ++t) {
            // ======== phase 1: z + r matmuls, rh production ========
            if (memoA < (unsigned)t) memoA = poll_loc32(p2l, t, nt, lane);
            if (j > 0 && memoB < (unsigned)(t + 1)) memoB = poll_rem32(p2r_low, t + 1, lane);

            // deferred cross-XCD h(t-1) store: drains in this phase's load shadow
            if (t > 0 && tid < 128)
                store8_coh(hrem + ((size_t)(j * 4 + ((t - 1) & 3)) * B_ + rb) * H_ + nt * 16 + rnl,
                           defer_lo, defer_hi);

            {
                const unsigned short* hl = hloc + (size_t)(j * 4 + ((t - 1) & 3)) * B_ * H_;
                const unsigned short* ir = (j > 0) ? hrem + (size_t)((j - 1) * 4 + (t & 3)) * B_ * H_ : nullptr;
#pragma unroll
                for (int kt = 0; kt < 16; ++kt) {
                    int g = khalf * 16 + kt;
                    if (g < T1) {
                        if (g < Tx) {
                            if (j == 0) afrag[kt] = *(const short8*)(xbf + (long)arow * (S_ * IN_) + (long)t * IN_ + g * 32 + koff);
                            else        afrag[kt] = load16_coh(ir + (long)arow * H_ + g * 32 + koff);
                        } else {
                            afrag[kt] = __builtin_nontemporal_load(
                                (const short8*)(hl + (long)arow * H_ + (g - Tx) * 32 + koff));
                        }
                    }
                }
            }
            {
                floatx4 az = {0.f, 0.f, 0.f, 0.f}, ar = {0.f, 0.f, 0.f, 0.f};
#pragma unroll
                for (int kt = 0; kt < 16; ++kt) {
                    int g = khalf * 16 + kt;
                    if (g < T1) {
                        short8 wr = wrl[khalf][kt][lane];
                        az = __builtin_amdgcn_mfma_f32_16x16x32_bf16(afrag[kt], wzc[kt], az, 0, 0, 0);
                        ar = __builtin_amdgcn_mfma_f32_16x16x32_bf16(afrag[kt], wr, ar, 0, 0, 0);
                    }
                }
#pragma unroll
                for (int i = 0; i < 4; ++i) {
                    int e = (quad * 4 + i) * 16 + l15;
                    part[v][0][e] = az[i];
                    part[v][1][e] = ar[i];
                }
            }
            __syncthreads();
            if (tid < 128) {
                float4 h4 = *(const float4*)(hst + rb * H_ + nt * 16 + rnl);
                unsigned lo = 0, hi = 0;
#pragma unroll
                for (int m = 0; m < 4; ++m) {
                    int e = bl * 16 + rnl + m;
                    float zs = part[bq][0][e] + part[bq + 2][0][e];
                    float rs = part[bq][1][e] + part[bq + 2][1][e];
                    zacc[m] = zs;
                    hv[m] = h4[m];
                    float r = sigmoidf_(rs + brv4[m]);
                    unsigned p = (unsigned)f2bf(r * h4[m]) << (16 * (m & 1));
                    if (m < 2) lo |= p; else hi |= p;
                }
                unsigned long long pk = (unsigned long long)lo | ((unsigned long long)hi << 32);
                __builtin_nontemporal_store(pk, (unsigned long long*)(rh_j + rb * H_ + nt * 16 + rnl));
            }
            VDRAIN();
            __syncthreads();
            if (tid == 0) {
                st_flag_loc(&p1l[nt], t + 1);
                if (j > 0) st_flag_rem(&p1r_self[nt], t + 1);
                if (t > 0) st_flag_rem(&p2r_self[nt], t);     // deferred h(t-1) now at LLC
            }

            // ======== phase 2: g matmul, h update ========
            if (memoC < (unsigned)(t + 1)) memoC = poll_loc32(p1l, t + 1, nt, lane);
            if (t >= 4) {
                unsigned thr = (unsigned)(t - 3);
                if (memoD < thr) memoD = poll_rem32(warfl, thr, lane);
            }
#pragma unroll
            for (int kt = 0; kt < 16; ++kt) {
                int g = khalf * 16 + kt;
                if (g >= Tx && g < T1)
                    afrag[kt] = __builtin_nontemporal_load(
                        (const short8*)((const unsigned short*)rh_j + (long)arow * H_ + (g - Tx) * 32 + koff));
            }
            {
                floatx4 ag = {0.f, 0.f, 0.f, 0.f};
#pragma unroll
                for (int kt = 0; kt < 16; ++kt) {
                    int g = khalf * 16 + kt;
                    if (g < T1)
                        ag = __builtin_amdgcn_mfma_f32_16x16x32_bf16(afrag[kt], wgc[kt], ag, 0, 0, 0);
                }
#pragma unroll
                for (int i = 0; i < 4; ++i) {
                    int e = (quad * 4 + i) * 16 + l15;
                    part[v][0][e] = ag[i];
                }
            }
            __syncthreads();
            if (tid < 128) {
                float4 h4n;
                unsigned lo = 0, hi = 0;
#pragma unroll
                for (int m = 0; m < 4; ++m) {
                    int e = bl * 16 + rnl + m;
                    float gs = part[bq][0][e] + part[bq + 2][0][e];
                    float gv = tanhf(gs + bgv4[m]);
                    float z  = sigmoidf_(zacc[m] + bzv4[m]);
                    float hn = z * hv[m] + (1.0f - z) * gv;
                    h4n[m] = hn;
                    unsigned p = (unsigned)f2bf(hn) << (16 * (m & 1));
                    if (m < 2) lo |= p; else hi |= p;
                }
                *(float4*)(hst + rb * H_ + nt * 16 + rnl) = h4n;   // WG-private
                unsigned long long pk = (unsigned long long)lo | ((unsigned long long)hi << 32);
                __builtin_nontemporal_store(pk,
                    (unsigned long long*)(hloc + ((size_t)(j * 4 + (t & 3)) * B_ + rb) * H_ + nt * 16 + rnl));
                defer_lo = lo; defer_hi = hi;                      // remote copy deferred
            }
            VDRAIN();
            __syncthreads();
            if (tid == 0) st_flag_loc(&p2l[nt], t + 1);
        }
        // ---- tail flush: publish final remote h(1023) ----
        if (tid < 128)
            store8_coh(hrem + ((size_t)(j * 4 + 3) * B_ + rb) * H_ + nt * 16 + rnl, defer_lo, defer_hi);
        VDRAIN();
        __syncthreads();
        if (tid == 0) st_flag_rem(&p2r_self[nt], S_);
    } else {
        // ================= output stage (XCD 3) =================
        unsigned memoE = 0;
#pragma unroll 1
        for (int t = 0; t < S_; ++t) {
            if (memoE < (unsigned)(t + 1)) memoE = poll_rem32(p2r2, t + 1, lane);
            const unsigned short* h2 = hrem + (size_t)(2 * 4 + (t & 3)) * B_ * H_;
            short8 aoc[8];
#pragma unroll
            for (int kt = 0; kt < 8; ++kt) {
                int g = khalf * 8 + kt;
                aoc[kt] = load16_coh(h2 + (long)arow * H_ + g * 32 + koff);
            }
            floatx4 ao = {0.f, 0.f, 0.f, 0.f};
#pragma unroll
            for (int kt = 0; kt < 8; ++kt)
                ao = __builtin_amdgcn_mfma_f32_16x16x32_bf16(aoc[kt], wc[kt], ao, 0, 0, 0);
#pragma unroll
            for (int i = 0; i < 4; ++i) {
                int e = (quad * 4 + i) * 16 + l15;
                part[v][0][e] = ao[i];
            }
            __syncthreads();
            if (tid < 128) {
                float4 o4;
#pragma unroll
                for (int m = 0; m < 4; ++m) {
                    int e = bl * 16 + rnl + m;
                    o4[m] = part[bq][0][e] + part[bq + 2][0][e] + bov4[m];
                }
                *(float4*)(out + (long)rb * (S_ * OUT_) + (long)t * OUT_ + ont * 16 + rnl) = o4;
            }
            VDRAIN();
            __syncthreads();
            if (tid == 0) st_flag_rem(&pofl[ont], t + 1);
        }
    }
}

// ---------------- post-pass: final hidden state ----------------
__global__ void __launch_bounds__(256) tail_kernel(const char* __restrict__ ws, float* __restrict__ out)
{
    int i = blockIdx.x * 256 + threadIdx.x;
    if (i < B_ * NL_ * H_) {
        int b = i / (NL_ * H_); int r = i % (NL_ * H_); int j = r / H_; int n = r % H_;
        out[B_ * S_ * OUT_ + i] = ((const float*)(ws + OFF_HST))[(j * B_ + b) * H_ + n];
    }
}

extern "C" void kernel_launch(void* const* d_in, const int* in_sizes, int n_in,
                              void* d_out, int out_size, void* d_ws, size_t ws_size,
                              hipStream_t stream)
{
    const float* x   = (const float*)d_in[0];
    const float* h0  = (const float*)d_in[1];
    const float* W0z = (const float*)d_in[2];  const float* b0z = (const float*)d_in[3];
    const float* W0r = (const float*)d_in[4];  const float* b0r = (const float*)d_in[5];
    const float* W0g = (const float*)d_in[6];  const float* b0g = (const float*)d_in[7];
    const float* Wxz = (const float*)d_in[8];  const float* bxz = (const float*)d_in[9];
    const float* Wxr = (const float*)d_in[10]; const float* bxr = (const float*)d_in[11];
    const float* Wxg = (const float*)d_in[12]; const float* bxg = (const float*)d_in[13];
    const float* Whz = (const float*)d_in[14];
    const float* Whr = (const float*)d_in[15];
    const float* Whg = (const float*)d_in[16];
    const float* Wout = (const float*)d_in[17]; const float* bout = (const float*)d_in[18];
    char* ws = (char*)d_ws;
    float* out = (float*)d_out;

    prep_kernel<<<dim3(4096), dim3(1024), 0, stream>>>(
        x, h0, W0z, W0r, W0g, Wxz, Wxr, Wxg, Whz, Whr, Whg, Wout, ws);

    gru_kernel<<<dim3(512), dim3(256), 0, stream>>>(
        ws, b0z, b0r, b0g, bxz, bxr, bxg, bout, out);

    tail_kernel<<<dim3(192), dim3(256), 0, stream>>>((const char*)ws, out);
}

// Round 9
// 7582.243 us; speedup vs baseline: 3.2575x; 1.0741x over previous
//
#include <hip/hip_runtime.h>
#include <cstdint>
#include <cstddef>

// ---------------- problem constants ----------------
#define B_   32
#define S_   1024
#define IN_  128
#define H_   512
#define OUT_ 128
#define NL_  3

typedef __attribute__((ext_vector_type(8))) short short8;   // 8 bf16 (4 VGPRs)
typedef __attribute__((ext_vector_type(4))) float floatx4;  // MFMA C/D
typedef __attribute__((ext_vector_type(2))) unsigned uint2v;

// ---------------- workspace layout (bytes) ----------------
constexpr size_t OFF_CLAIM = 0;        // 8 uints
constexpr size_t OFF_P1L   = 128;      // [3][32] phase1-done, local (L2 nt)
constexpr size_t OFF_P2L   = 512;      // [3][32] phase2-done, local
constexpr size_t OFF_P1R   = 896;      // [3][32] phase1-done, remote (sc1)
constexpr size_t OFF_P2R   = 1280;     // [3][32] phase2-done, remote
constexpr size_t OFF_PO    = 1664;     // [32] out-done (8 real + 24 padded huge)
constexpr size_t OFF_W0Z  = 8192;                     // 512x128 bf16
constexpr size_t OFF_W0R  = OFF_W0Z + 131072;
constexpr size_t OFF_W0G  = OFF_W0R + 131072;
constexpr size_t OFF_WXZ  = OFF_W0G + 131072;         // 512x512 bf16 each
constexpr size_t OFF_WXR  = OFF_WXZ + 524288;
constexpr size_t OFF_WXG  = OFF_WXR + 524288;
constexpr size_t OFF_WHZ  = OFF_WXG + 524288;
constexpr size_t OFF_WHR  = OFF_WHZ + 524288;
constexpr size_t OFF_WHG  = OFF_WHR + 524288;
constexpr size_t OFF_WOUT = OFF_WHG + 524288;         // 128x512 bf16
constexpr size_t OFF_XBF  = OFF_WOUT + 131072;        // x bf16 [32][1024][128]
constexpr size_t OFF_HST  = OFF_XBF + 8388608;        // f32 h state [3][32][512] (WG-private)
constexpr size_t OFF_HLOC = OFF_HST + 196608;         // bf16 h [3][4][32][512] intra-XCD (nt/L2)
constexpr size_t OFF_HREM = OFF_HLOC + 393216;        // bf16 h [3][4][32][512] cross-XCD (sc1)
constexpr size_t OFF_RH   = OFF_HREM + 393216;        // bf16 r*h [3][32][512] intra-XCD (nt/L2)
// end = OFF_RH + 98304 = 13,148,160 bytes

__device__ __forceinline__ unsigned short f2bf(float f) {
    unsigned u = __float_as_uint(f);
    unsigned r = (u + 0x7FFFu + ((u >> 16) & 1u)) >> 16;
    return (unsigned short)r;
}
__device__ __forceinline__ float sigmoidf_(float x) { return 1.0f / (1.0f + __expf(-x)); }
__device__ __forceinline__ float tanhf_(float x) {
    float e = __expf(2.0f * x);
    return 1.0f - 2.0f / (e + 1.0f);
}

// ---- cross-XCD (LLC) helpers — proven r4-r7 recipe ----
__device__ __forceinline__ short8 load16_coh(const void* p) {
    union { unsigned long long u[2]; short8 s; } r;
    const unsigned long long* q = (const unsigned long long*)p;
    r.u[0] = __hip_atomic_load(q,     __ATOMIC_RELAXED, __HIP_MEMORY_SCOPE_AGENT);
    r.u[1] = __hip_atomic_load(q + 1, __ATOMIC_RELAXED, __HIP_MEMORY_SCOPE_AGENT);
    return r.s;
}
__device__ __forceinline__ void store8_coh(void* p, unsigned lo, unsigned hi) {
    uint2v u; u.x = lo; u.y = hi;
    asm volatile("global_store_dwordx2 %0, %1, off sc0 sc1" :: "v"(p), "v"(u) : "memory");
}

#define VDRAIN() asm volatile("s_waitcnt vmcnt(0)" ::: "memory")

// ---- flag helpers (r7-proven) ----
__device__ __forceinline__ unsigned wave_min32_bcast(unsigned f) {
#pragma unroll
    for (int off = 1; off < 32; off <<= 1) {
        unsigned o = (unsigned)__shfl_xor((int)f, off, 64);
        f = (o < f) ? o : f;
    }
    return (unsigned)__shfl((int)f, 0, 64);
}
__device__ __forceinline__ unsigned poll_loc32(const unsigned* flags, unsigned thr, int skip, int lane) {
    const unsigned* p = flags + (lane & 31);
    unsigned f;
    for (;;) {
        f = __builtin_nontemporal_load(p);
        if ((lane & 31) == skip) f = 0xFFFFFFFFu;
        if (__all((int)(f >= thr))) break;
        asm volatile("s_sleep 1" ::: "memory");
    }
    return wave_min32_bcast(f);
}
__device__ __forceinline__ unsigned poll_rem32(const unsigned* flags, unsigned thr, int lane) {
    const unsigned* p = flags + (lane & 31);
    unsigned f;
    for (;;) {
        f = __hip_atomic_load(p, __ATOMIC_RELAXED, __HIP_MEMORY_SCOPE_AGENT);
        if (__all((int)(f >= thr))) break;
        asm volatile("s_sleep 2" ::: "memory");
    }
    return wave_min32_bcast(f);
}
__device__ __forceinline__ void st_flag_loc(unsigned* p, unsigned v) { __builtin_nontemporal_store(v, p); }
__device__ __forceinline__ void st_flag_rem(unsigned* p, unsigned v) {
    __hip_atomic_store(p, v, __ATOMIC_RELAXED, __HIP_MEMORY_SCOPE_AGENT);
}

// ---------------- pre-pass: converts + init ----------------
__global__ void __launch_bounds__(1024) prep_kernel(
    const float* __restrict__ x, const float* __restrict__ h0,
    const float* __restrict__ W0z, const float* __restrict__ W0r, const float* __restrict__ W0g,
    const float* __restrict__ Wxz, const float* __restrict__ Wxr, const float* __restrict__ Wxg,
    const float* __restrict__ Whz, const float* __restrict__ Whr, const float* __restrict__ Whg,
    const float* __restrict__ Wout, char* __restrict__ ws)
{
    int i = blockIdx.x * 1024 + threadIdx.x;
    unsigned short* xbf = (unsigned short*)(ws + OFF_XBF);
    if (i < B_ * S_ * IN_) xbf[i] = f2bf(x[i]);
    if (i < 65536) {
        ((unsigned short*)(ws + OFF_W0Z))[i]  = f2bf(W0z[i]);
        ((unsigned short*)(ws + OFF_W0R))[i]  = f2bf(W0r[i]);
        ((unsigned short*)(ws + OFF_W0G))[i]  = f2bf(W0g[i]);
        ((unsigned short*)(ws + OFF_WOUT))[i] = f2bf(Wout[i]);
    }
    if (i < 262144) {
        ((unsigned short*)(ws + OFF_WXZ))[i] = f2bf(Wxz[i]);
        ((unsigned short*)(ws + OFF_WXR))[i] = f2bf(Wxr[i]);
        ((unsigned short*)(ws + OFF_WXG))[i] = f2bf(Wxg[i]);
        ((unsigned short*)(ws + OFF_WHZ))[i] = f2bf(Whz[i]);
        ((unsigned short*)(ws + OFF_WHR))[i] = f2bf(Whr[i]);
        ((unsigned short*)(ws + OFF_WHG))[i] = f2bf(Whg[i]);
    }
    if (i < B_ * NL_ * H_) {
        int b = i / (NL_ * H_); int r = i % (NL_ * H_); int j = r / H_; int n = r % H_;
        float v = h0[i];
        ((float*)(ws + OFF_HST))[(j * B_ + b) * H_ + n] = v;
        // phase1 of t=0 reads hloc slot (0-1)&3 = 3
        ((unsigned short*)(ws + OFF_HLOC))[((j * 4 + 3) * B_ + b) * H_ + n] = f2bf(v);
    }
    if (i < 448) {   // zero claim + all flag groups; pad PO slots 8..31 with huge
        unsigned v = 0u;
        int rel = i - (int)(OFF_PO / 4);
        if (rel >= 8 && rel < 32) v = 0xFFFFFFFFu;
        ((unsigned*)ws)[i] = v;
    }
}

// ---------------- the scan: XCD-claimed roles, p2p flags, pre-poll compute ----------------
__global__ void __launch_bounds__(256, 1) gru_kernel(char* ws,
    const float* __restrict__ b0z, const float* __restrict__ b0r, const float* __restrict__ b0g,
    const float* __restrict__ bxz, const float* __restrict__ bxr, const float* __restrict__ bxg,
    const float* __restrict__ bout, float* __restrict__ out)
{
    // ---- role claim: layer j on XCD j (32 WGs), out on XCD 3 (8 WGs) ----
    __shared__ int role_s;
    if (threadIdx.x == 0) {
        int xcc;
        asm volatile("s_getreg_b32 %0, hwreg(HW_REG_XCC_ID, 0, 32)" : "=s"(xcc));
        xcc &= 7;
        int role = -1;
        unsigned slot = atomicAdd((unsigned*)(ws + OFF_CLAIM) + xcc, 1u);
        if (xcc < 3)       { if (slot < 32) role = xcc * 32 + (int)slot; }
        else if (xcc == 3) { if (slot < 8)  role = 96 + (int)slot; }
        role_s = role;
    }
    __syncthreads();
    const int role = role_s;
    if (role < 0) return;

    const bool is_out = (role >= 96);
    const int tid   = threadIdx.x;
    const int v     = tid >> 6;
    const int lane  = tid & 63;
    const int btile = v & 1;
    const int khalf = v >> 1;
    const int l15   = lane & 15;
    const int quad  = lane >> 4;
    const int koff  = quad * 8;
    const int arow  = btile * 16 + l15;

    __shared__ float part[4][2][256];          // 8 KB
    __shared__ short8 wrl[2][16][64];          // 32 KB r-gate weight frags

    // ----- layer setup -----
    const int j  = is_out ? 0 : (role >> 5);
    const int nt = role & 31;
    const int nrow = nt * 16 + l15;
    const int Tx = (j == 0) ? 4 : 16;
    const int T1 = Tx + 16;
    short8 wzc[16], wgc[16];
    const short* xbf = (const short*)(ws + OFF_XBF);
    float* hst = (float*)(ws + OFF_HST) + (size_t)j * B_ * H_;
    unsigned short* hloc = (unsigned short*)(ws + OFF_HLOC);
    unsigned short* hrem = (unsigned short*)(ws + OFF_HREM);
    unsigned short* rh_j = (unsigned short*)(ws + OFF_RH) + (size_t)j * B_ * H_;

    unsigned* p1l = (unsigned*)(ws + OFF_P1L) + j * 32;
    unsigned* p2l = (unsigned*)(ws + OFF_P2L) + j * 32;
    unsigned* p1r_self = (unsigned*)(ws + OFF_P1R) + j * 32;
    unsigned* p2r_self = (unsigned*)(ws + OFF_P2R) + j * 32;
    unsigned* p2r_low  = (unsigned*)(ws + OFF_P2R) + (j - 1) * 32;   // j>=1 only
    unsigned* warfl    = (j < 2) ? (unsigned*)(ws + OFF_P1R) + (j + 1) * 32
                                 : (unsigned*)(ws + OFF_PO);
    unsigned* p2r2 = (unsigned*)(ws + OFF_P2R) + 2 * 32;
    unsigned* pofl = (unsigned*)(ws + OFF_PO);

    // ----- out setup -----
    const int ont = role - 96;
    short8 wc[8];

    // ----- reducer mapping (tid<128): owns (b = tid>>2, 4 consecutive n) -----
    const int rb  = tid >> 2;
    const int bq  = rb >> 4;
    const int bl  = rb & 15;
    const int rnl = (tid & 3) * 4;
    float4 brv4 = {0,0,0,0}, bzv4 = {0,0,0,0}, bgv4 = {0,0,0,0}, bov4 = {0,0,0,0};

    if (!is_out) {
        const float* bz_b = (j == 0) ? b0z : bxz;
        const float* br_b = (j == 0) ? b0r : bxr;
        const float* bg_b = (j == 0) ? b0g : bxg;
        if (tid < 128) {
            bzv4 = *(const float4*)(bz_b + nt * 16 + rnl);
            brv4 = *(const float4*)(br_b + nt * 16 + rnl);
            bgv4 = *(const float4*)(bg_b + nt * 16 + rnl);
        }
        const int strx = (j == 0) ? IN_ : H_;
        const short* Wz_x = (const short*)(ws + ((j == 0) ? OFF_W0Z : OFF_WXZ));
        const short* Wr_x = (const short*)(ws + ((j == 0) ? OFF_W0R : OFF_WXR));
        const short* Wg_x = (const short*)(ws + ((j == 0) ? OFF_W0G : OFF_WXG));
        const short* Wz_h = (const short*)(ws + OFF_WHZ);
        const short* Wr_h = (const short*)(ws + OFF_WHR);
        const short* Wg_h = (const short*)(ws + OFF_WHG);
#pragma unroll
        for (int kt = 0; kt < 16; ++kt) {
            int g = khalf * 16 + kt;
            if (g < T1) {
                if (g < Tx) {
                    long o = (long)nrow * strx + g * 32 + koff;
                    wzc[kt] = *(const short8*)(Wz_x + o);
                    wgc[kt] = *(const short8*)(Wg_x + o);
                    wrl[khalf][kt][lane] = *(const short8*)(Wr_x + o);
                } else {
                    long o = (long)nrow * H_ + (g - Tx) * 32 + koff;
                    wzc[kt] = *(const short8*)(Wz_h + o);
                    wgc[kt] = *(const short8*)(Wg_h + o);
                    wrl[khalf][kt][lane] = *(const short8*)(Wr_h + o);
                }
            }
        }
    } else {
        const short* Wo = (const short*)(ws + OFF_WOUT);
        if (tid < 128) bov4 = *(const float4*)(bout + ont * 16 + rnl);
#pragma unroll
        for (int kt = 0; kt < 8; ++kt) {
            int g = khalf * 8 + kt;
            wc[kt] = *(const short8*)(Wo + (long)(ont * 16 + l15) * H_ + g * 32 + koff);
        }
    }
    __syncthreads();

    if (!is_out) {
        short8 afrag[16];
        float zacc[4], hv[4];
        unsigned memoA = 0, memoB = 0, memoC = 0, memoD = 0;

#pragma unroll 1
        for (int t = 0; t < S_; ++t) {
            // ======== phase 1: z + r matmuls, rh production ========
            // --- pre-poll: inp half (independent of local h(t-1)) ---
            if (j > 0 && memoB < (unsigned)(t + 1)) memoB = poll_rem32(p2r_low, t + 1, lane);
            {
                const unsigned short* ir = (j > 0) ? hrem + (size_t)((j - 1) * 4 + (t & 3)) * B_ * H_ : nullptr;
#pragma unroll
                for (int kt = 0; kt < 16; ++kt) {
                    int g = khalf * 16 + kt;
                    if (g < Tx) {
                        if (j == 0) afrag[kt] = *(const short8*)(xbf + (long)arow * (S_ * IN_) + (long)t * IN_ + g * 32 + koff);
                        else        afrag[kt] = load16_coh(ir + (long)arow * H_ + g * 32 + koff);
                    }
                }
            }
            floatx4 az = {0.f, 0.f, 0.f, 0.f}, ar = {0.f, 0.f, 0.f, 0.f};
#pragma unroll
            for (int kt = 0; kt < 16; ++kt) {
                int g = khalf * 16 + kt;
                if (g < Tx) {
                    short8 wr = wrl[khalf][kt][lane];
                    az = __builtin_amdgcn_mfma_f32_16x16x32_bf16(afrag[kt], wzc[kt], az, 0, 0, 0);
                    ar = __builtin_amdgcn_mfma_f32_16x16x32_bf16(afrag[kt], wr, ar, 0, 0, 0);
                }
            }
            // --- post-poll: h(t-1) half ---
            if (memoA < (unsigned)t) memoA = poll_loc32(p2l, t, nt, lane);
            {
                const unsigned short* hl = hloc + (size_t)(j * 4 + ((t - 1) & 3)) * B_ * H_;
#pragma unroll
                for (int kt = 0; kt < 16; ++kt) {
                    int g = khalf * 16 + kt;
                    if (g >= Tx && g < T1)
                        afrag[kt] = __builtin_nontemporal_load(
                            (const short8*)(hl + (long)arow * H_ + (g - Tx) * 32 + koff));
                }
            }
#pragma unroll
            for (int kt = 0; kt < 16; ++kt) {
                int g = khalf * 16 + kt;
                if (g >= Tx && g < T1) {
                    short8 wr = wrl[khalf][kt][lane];
                    az = __builtin_amdgcn_mfma_f32_16x16x32_bf16(afrag[kt], wzc[kt], az, 0, 0, 0);
                    ar = __builtin_amdgcn_mfma_f32_16x16x32_bf16(afrag[kt], wr, ar, 0, 0, 0);
                }
            }
#pragma unroll
            for (int i = 0; i < 4; ++i) {
                int e = (quad * 4 + i) * 16 + l15;
                part[v][0][e] = az[i];
                part[v][1][e] = ar[i];
            }
            __syncthreads();
            if (tid < 128) {
                float4 h4 = *(const float4*)(hst + rb * H_ + nt * 16 + rnl);
                unsigned lo = 0, hi = 0;
#pragma unroll
                for (int m = 0; m < 4; ++m) {
                    int e = bl * 16 + rnl + m;
                    float zs = part[bq][0][e] + part[bq + 2][0][e];
                    float rs = part[bq][1][e] + part[bq + 2][1][e];
                    zacc[m] = zs;
                    hv[m] = h4[m];
                    float r = sigmoidf_(rs + brv4[m]);
                    unsigned p = (unsigned)f2bf(r * h4[m]) << (16 * (m & 1));
                    if (m < 2) lo |= p; else hi |= p;
                }
                unsigned long long pk = (unsigned long long)lo | ((unsigned long long)hi << 32);
                __builtin_nontemporal_store(pk, (unsigned long long*)(rh_j + rb * H_ + nt * 16 + rnl));
            }
            VDRAIN();
            __syncthreads();
            if (tid == 0) {
                st_flag_loc(&p1l[nt], t + 1);
                if (j > 0) st_flag_rem(&p1r_self[nt], t + 1);
            }

            // ======== phase 2: g matmul, h update ========
            if (t >= 4 && memoD < (unsigned)(t - 3)) memoD = poll_rem32(warfl, t - 3, lane);
            // --- pre-poll: inp half on retained afrag (zero loads) ---
            floatx4 ag = {0.f, 0.f, 0.f, 0.f};
#pragma unroll
            for (int kt = 0; kt < 16; ++kt) {
                int g = khalf * 16 + kt;
                if (g < Tx)
                    ag = __builtin_amdgcn_mfma_f32_16x16x32_bf16(afrag[kt], wgc[kt], ag, 0, 0, 0);
            }
            // --- post-poll: rh half ---
            if (memoC < (unsigned)(t + 1)) memoC = poll_loc32(p1l, t + 1, nt, lane);
#pragma unroll
            for (int kt = 0; kt < 16; ++kt) {
                int g = khalf * 16 + kt;
                if (g >= Tx && g < T1)
                    afrag[kt] = __builtin_nontemporal_load(
                        (const short8*)((const unsigned short*)rh_j + (long)arow * H_ + (g - Tx) * 32 + koff));
            }
#pragma unroll
            for (int kt = 0; kt < 16; ++kt) {
                int g = khalf * 16 + kt;
                if (g >= Tx && g < T1)
                    ag = __builtin_amdgcn_mfma_f32_16x16x32_bf16(afrag[kt], wgc[kt], ag, 0, 0, 0);
            }
#pragma unroll
            for (int i = 0; i < 4; ++i) {
                int e = (quad * 4 + i) * 16 + l15;
                part[v][0][e] = ag[i];
            }
            __syncthreads();
            if (tid < 128) {
                float4 h4n;
                unsigned lo = 0, hi = 0;
#pragma unroll
                for (int m = 0; m < 4; ++m) {
                    int e = bl * 16 + rnl + m;
                    float gs = part[bq][0][e] + part[bq + 2][0][e];
                    float gv = tanhf_(gs + bgv4[m]);
                    float z  = sigmoidf_(zacc[m] + bzv4[m]);
                    float hn = z * hv[m] + (1.0f - z) * gv;
                    h4n[m] = hn;
                    unsigned p = (unsigned)f2bf(hn) << (16 * (m & 1));
                    if (m < 2) lo |= p; else hi |= p;
                }
                *(float4*)(hst + rb * H_ + nt * 16 + rnl) = h4n;   // WG-private
                unsigned long long pk = (unsigned long long)lo | ((unsigned long long)hi << 32);
                __builtin_nontemporal_store(pk,
                    (unsigned long long*)(hloc + ((size_t)(j * 4 + (t & 3)) * B_ + rb) * H_ + nt * 16 + rnl));
                store8_coh(hrem + ((size_t)(j * 4 + (t & 3)) * B_ + rb) * H_ + nt * 16 + rnl, lo, hi);
            }
            VDRAIN();
            __syncthreads();
            if (tid == 0) {
                st_flag_loc(&p2l[nt], t + 1);
                st_flag_rem(&p2r_self[nt], t + 1);
            }
        }
    } else {
        // ================= output stage (XCD 3) =================
        unsigned memoE = 0;
#pragma unroll 1
        for (int t = 0; t < S_; ++t) {
            if (memoE < (unsigned)(t + 1)) memoE = poll_rem32(p2r2, t + 1, lane);
            const unsigned short* h2 = hrem + (size_t)(2 * 4 + (t & 3)) * B_ * H_;
            short8 aoc[8];
#pragma unroll
            for (int kt = 0; kt < 8; ++kt) {
                int g = khalf * 8 + kt;
                aoc[kt] = load16_coh(h2 + (long)arow * H_ + g * 32 + koff);
            }
            floatx4 ao = {0.f, 0.f, 0.f, 0.f};
#pragma unroll
            for (int kt = 0; kt < 8; ++kt)
                ao = __builtin_amdgcn_mfma_f32_16x16x32_bf16(aoc[kt], wc[kt], ao, 0, 0, 0);
#pragma unroll
            for (int i = 0; i < 4; ++i) {
                int e = (quad * 4 + i) * 16 + l15;
                part[v][0][e] = ao[i];
            }
            __syncthreads();
            if (tid < 128) {
                float4 o4;
#pragma unroll
                for (int m = 0; m < 4; ++m) {
                    int e = bl * 16 + rnl + m;
                    o4[m] = part[bq][0][e] + part[bq + 2][0][e] + bov4[m];
                }
                *(float4*)(out + (long)rb * (S_ * OUT_) + (long)t * OUT_ + ont * 16 + rnl) = o4;
            }
            VDRAIN();
            __syncthreads();
            if (tid == 0) st_flag_rem(&pofl[ont], t + 1);
        }
    }
}

// ---------------- post-pass: final hidden state ----------------
__global__ void __launch_bounds__(256) tail_kernel(const char* __restrict__ ws, float* __restrict__ out)
{
    int i = blockIdx.x * 256 + threadIdx.x;
    if (i < B_ * NL_ * H_) {
        int b = i / (NL_ * H_); int r = i % (NL_ * H_); int j = r / H_; int n = r % H_;
        out[B_ * S_ * OUT_ + i] = ((const float*)(ws + OFF_HST))[(j * B_ + b) * H_ + n];
    }
}

extern "C" void kernel_launch(void* const* d_in, const int* in_sizes, int n_in,
                              void* d_out, int out_size, void* d_ws, size_t ws_size,
                              hipStream_t stream)
{
    const float* x   = (const float*)d_in[0];
    const float* h0  = (const float*)d_in[1];
    const float* W0z = (const float*)d_in[2];  const float* b0z = (const float*)d_in[3];
    const float* W0r = (const float*)d_in[4];  const float* b0r = (const float*)d_in[5];
    const float* W0g = (const float*)d_in[6];  const float* b0g = (const float*)d_in[7];
    const float* Wxz = (const float*)d_in[8];  const float* bxz = (const float*)d_in[9];
    const float* Wxr = (const float*)d_in[10]; const float* bxr = (const float*)d_in[11];
    const float* Wxg = (const float*)d_in[12]; const float* bxg = (const float*)d_in[13];
    const float* Whz = (const float*)d_in[14];
    const float* Whr = (const float*)d_in[15];
    const float* Whg = (const float*)d_in[16];
    const float* Wout = (const float*)d_in[17]; const float* bout = (const float*)d_in[18];
    char* ws = (char*)d_ws;
    float* out = (float*)d_out;

    prep_kernel<<<dim3(4096), dim3(1024), 0, stream>>>(
        x, h0, W0z, W0r, W0g, Wxz, Wxr, Wxg, Whz, Whr, Whg, Wout, ws);

    gru_kernel<<<dim3(512), dim3(256), 0, stream>>>(
        ws, b0z, b0r, b0g, bxz, bxr, bxg, bout, out);

    tail_kernel<<<dim3(192), dim3(256), 0, stream>>>((const char*)ws, out);
}